// Round 4
// baseline (76.331 us; speedup 1.0000x reference)
//
#include <hip/hip_runtime.h>
#include <stdint.h>
#include <math.h>

// ---------------------------------------------------------------------------
// SubsetItems, round 4: same bit-exact math (absmax 0.0 in r1-r3), two
// dispatches:
//   k1 noise          -> packed 64-bit total-order keys; zeroes done[8]
//   k2 rank+finalize  -> u8 partial rank counts (cnt<=64), then last-block-
//                        per-row finalize (threadfence release/acquire +
//                        atomicAdd(done[row]) signal; no spins).
// Partial matrix u8: 2 MB (was 8 MB int). Finalize reads 256 KB/row coalesced.
// ---------------------------------------------------------------------------

#define RANK_G 64
#define JCHUNK (4096 / RANK_G)   // 64 -> per-(i,g) count <= 64, fits u8
#define IPT    16

struct TF2 { uint32_t a, b; };

__host__ __device__ inline TF2 threefry2x32(uint32_t k0, uint32_t k1,
                                            uint32_t x0, uint32_t x1) {
  const uint32_t ks2 = k0 ^ k1 ^ 0x1BD11BDAu;
#define TF_ROT(v, d) (uint32_t)(((v) << (d)) | ((v) >> (32 - (d))))
#define TF_RND(r) do { x0 += x1; x1 = TF_ROT(x1, r); x1 ^= x0; } while (0)
  x0 += k0; x1 += k1;
  TF_RND(13); TF_RND(15); TF_RND(26); TF_RND(6);
  x0 += k1; x1 += ks2 + 1u;
  TF_RND(17); TF_RND(29); TF_RND(16); TF_RND(24);
  x0 += ks2; x1 += k0 + 2u;
  TF_RND(13); TF_RND(15); TF_RND(26); TF_RND(6);
  x0 += k0; x1 += k1 + 3u;
  TF_RND(17); TF_RND(29); TF_RND(16); TF_RND(24);
  x0 += k1; x1 += ks2 + 4u;
  TF_RND(13); TF_RND(15); TF_RND(26); TF_RND(6);
  x0 += ks2; x1 += k0 + 5u;
#undef TF_RND
#undef TF_ROT
  return {x0, x1};
}

__host__ __device__ __forceinline__ uint32_t random_bits_at(uint32_t ka, uint32_t kb,
                                                            uint32_t idx) {
  TF2 r = threefry2x32(ka, kb, 0u, idx);
  return r.a ^ r.b;
}

// XLA/CHLO ErfInv f32 (bit-exact, verified r1-r3).
__device__ __forceinline__ float erfinv_f32_xla(float x) {
  float xx = __fmul_rn(x, x);
  float v  = -xx;
  float w;
  if (fabsf(v) < 1e-4f) {
    float t = __fmul_rn(__fadd_rn(__fmul_rn(-0.5f, v), 1.0f), v);
    w = -t;
  } else {
    float t = __fadd_rn(v, 1.0f);
    w = -(float)log((double)t);
  }
  float p;
  if (w < 5.0f) {
    float ww = __fadd_rn(w, -2.5f);
    p = 2.81022636e-08f;
    p = __fadd_rn( 3.43273939e-07f, __fmul_rn(p, ww));
    p = __fadd_rn(-3.5233877e-06f,  __fmul_rn(p, ww));
    p = __fadd_rn(-4.39150654e-06f, __fmul_rn(p, ww));
    p = __fadd_rn( 0.00021858087f,  __fmul_rn(p, ww));
    p = __fadd_rn(-0.00125372503f,  __fmul_rn(p, ww));
    p = __fadd_rn(-0.00417768164f,  __fmul_rn(p, ww));
    p = __fadd_rn( 0.246640727f,    __fmul_rn(p, ww));
    p = __fadd_rn( 1.50140941f,     __fmul_rn(p, ww));
  } else {
    float ww = __fadd_rn(__fsqrt_rn(w), -3.0f);
    p = -0.000200214257f;
    p = __fadd_rn( 0.000100950558f, __fmul_rn(p, ww));
    p = __fadd_rn( 0.00134934322f,  __fmul_rn(p, ww));
    p = __fadd_rn(-0.00367342844f,  __fmul_rn(p, ww));
    p = __fadd_rn( 0.00573950773f,  __fmul_rn(p, ww));
    p = __fadd_rn(-0.0076224613f,   __fmul_rn(p, ww));
    p = __fadd_rn( 0.00943887047f,  __fmul_rn(p, ww));
    p = __fadd_rn( 1.00167406f,     __fmul_rn(p, ww));
    p = __fadd_rn( 2.83297682f,     __fmul_rn(p, ww));
  }
  return __fmul_rn(p, x);
}

// Kernel 1: x_noised -> packed 64-bit total-order key; zero done[].
__global__ __launch_bounds__(64)
void noise_kernel(const float* __restrict__ scores, uint64_t* __restrict__ k64,
                  uint32_t* __restrict__ done,
                  uint32_t k1a, uint32_t k1b, uint32_t k3a, uint32_t k3b,
                  uint32_t rowmask) {
  if (blockIdx.x == 0 && threadIdx.x < 8) done[threadIdx.x] = 0;

  int e = blockIdx.x * 64 + threadIdx.x;   // 32768
  int b = e >> 12;

  uint32_t mbits = random_bits_at(k1a, k1b, (uint32_t)e);
  bool mask = ((mbits >> 9) <= 838860u) && ((rowmask >> b) & 1u);

  float s  = scores[e];
  float sf = scores[32767 - e];
  float v  = mask ? fmaxf(s, sf) : s;
  float x  = fminf(fmaxf(v, -1.0f), 1.0f);

  uint32_t nbits = random_bits_at(k3a, k3b, (uint32_t)e);
  float f   = __uint_as_float((nbits >> 9) | 0x3f800000u);
  float f01 = __fadd_rn(f, -1.0f);
  const float lo = __uint_as_float(0xBF7FFFFFu);
  float u = __fadd_rn(__fmul_rn(f01, 2.0f), lo);
  u = fmaxf(lo, u);
  float p    = erfinv_f32_xla(u);
  float nrm  = __fmul_rn(__uint_as_float(0x3FB504F3u), p);
  float nois = __fmul_rn(nrm, 0.0009765625f);
  float xnv  = __fadd_rn(x, nois);

  uint32_t ub = __float_as_uint(xnv);
  uint32_t tk = (ub & 0x80000000u) ? ~ub : (ub | 0x80000000u);
  k64[e] = ((uint64_t)tk << 32) | (uint32_t)(e & 4095);
}

// Kernel 2: partial ranks (u8) + last-block-per-row finalize.
__global__ __launch_bounds__(256)
void rank_finalize_kernel(const uint64_t* __restrict__ k64,
                          uint8_t* __restrict__ partial,
                          uint32_t* __restrict__ done,
                          float* __restrict__ out) {
  int row = blockIdx.x >> 6;              // /RANK_G
  int g   = blockIdx.x & (RANK_G - 1);
  const uint64_t* rk = k64 + row * 4096;
  int t = threadIdx.x;

  uint64_t ki[IPT];
  int cnt[IPT];
#pragma unroll
  for (int m = 0; m < IPT; ++m) { ki[m] = rk[m * 256 + t]; cnt[m] = 0; }

  int j0 = g * JCHUNK;
#pragma unroll 4
  for (int j = j0; j < j0 + JCHUNK; ++j) {
    uint64_t kj = rk[j];                  // wave-uniform -> scalar load
#pragma unroll
    for (int m = 0; m < IPT; ++m) cnt[m] += (int)(kj < ki[m]);
  }

  uint8_t* pp = partial + (row * RANK_G + g) * 4096;
#pragma unroll
  for (int m = 0; m < IPT; ++m) pp[m * 256 + t] = (uint8_t)cnt[m];

  // --- signal: this block's partials are done ---
  __syncthreads();          // drain vmcnt: all 4 waves' stores are in L2
  __threadfence();          // agent-scope release: write back L2
  __shared__ int slast;
  if (t == 0)
    slast = (atomicAdd(&done[row], 1u) == (uint32_t)(RANK_G - 1));
  __syncthreads();
  if (!slast) return;

  // --- last block of this row: finalize ---
  __threadfence();          // acquire: invalidate stale L1/L2 lines

  const uint8_t* prow = partial + row * RANK_G * 4096;
  int acc[16];
#pragma unroll
  for (int q = 0; q < 16; ++q) acc[q] = 0;

#pragma unroll 4
  for (int gg = 0; gg < RANK_G; ++gg) {
    const uint32_t* p32 = (const uint32_t*)(prow + gg * 4096 + t * 16);
    uint32_t w0 = p32[0], w1 = p32[1], w2 = p32[2], w3 = p32[3];
#pragma unroll
    for (int bq = 0; bq < 4; ++bq) {
      acc[bq]      += (int)((w0 >> (8 * bq)) & 0xFFu);
      acc[4 + bq]  += (int)((w1 >> (8 * bq)) & 0xFFu);
      acc[8 + bq]  += (int)((w2 >> (8 * bq)) & 0xFFu);
      acc[12 + bq] += (int)((w3 >> (8 * bq)) & 0xFFu);
    }
  }

  int ibase = t * 16;
#pragma unroll
  for (int q = 0; q < 16; ++q) {
    int r = acc[q];
    if (r >= 2048) {
      int j = r - 2048;
      out[row * 2048 + j] = (float)(ibase + q);
      out[16384 + row * 2048 + j] = fminf(__fdiv_rn((float)j, 204.8f), 1.0f);
    }
  }
}

extern "C" void kernel_launch(void* const* d_in, const int* in_sizes, int n_in,
                              void* d_out, int out_size, void* d_ws, size_t ws_size,
                              hipStream_t stream) {
  const float* scores = (const float*)d_in[0];
  float* out = (float*)d_out;

  uint64_t* k64     = (uint64_t*)d_ws;                        // 256 KB
  uint8_t*  partial = (uint8_t*)d_ws + 32768 * 8;             // 2 MB
  uint32_t* done    = (uint32_t*)((uint8_t*)d_ws + 32768 * 8 + 8 * RANK_G * 4096);

  // split(key(42), 3), partitionable layout (verified r1)
  TF2 K1 = threefry2x32(0u, 42u, 0u, 0u);
  TF2 K2 = threefry2x32(0u, 42u, 0u, 1u);
  TF2 K3 = threefry2x32(0u, 42u, 0u, 2u);

  // batch_mask rows on host: uniform(k2,(8,1)) < 0.75
  uint32_t rowmask = 0;
  for (uint32_t b = 0; b < 8; ++b) {
    uint32_t bits = random_bits_at(K2.a, K2.b, b);
    if ((bits >> 9) < 6291456u) rowmask |= (1u << b);
  }

  noise_kernel<<<512, 64, 0, stream>>>(scores, k64, done,
                                       K1.a, K1.b, K3.a, K3.b, rowmask);
  rank_finalize_kernel<<<8 * RANK_G, 256, 0, stream>>>(k64, partial, done, out);
}

// Round 5
// 33.714 us; speedup vs baseline: 2.2640x; 2.2640x over previous
//
#include <hip/hip_runtime.h>
#include <stdint.h>
#include <math.h>

// ---------------------------------------------------------------------------
// SubsetItems, round 5: bit-exact math (absmax 0.0 r1-r4). Two dispatches,
// fence-free cross-block handoff (r4 lesson: per-block __threadfence =
// buffer_wbl2 full-L2 scan = 66us; NEVER flush, go through the coherence pt):
//   k1 noise         -> packed 64-bit total-order keys; zeroes done[8]
//   k2 rank+finalize -> u8x4-packed partial counts via RELAXED SYSTEM-scope
//                       atomic stores (sc0 sc1 write-through, no wbl2),
//                       __syncthreads vmcnt drain, relaxed agent atomicAdd
//                       signal; last block per row reads partials back via
//                       RELAXED SYSTEM-scope atomic loads (cache-bypass).
// ---------------------------------------------------------------------------

#define RANK_G 64
#define JCHUNK (4096 / RANK_G)   // 64 -> per-(i,g) count <= 64, fits u8
#define IPT    16

struct TF2 { uint32_t a, b; };

__host__ __device__ inline TF2 threefry2x32(uint32_t k0, uint32_t k1,
                                            uint32_t x0, uint32_t x1) {
  const uint32_t ks2 = k0 ^ k1 ^ 0x1BD11BDAu;
#define TF_ROT(v, d) (uint32_t)(((v) << (d)) | ((v) >> (32 - (d))))
#define TF_RND(r) do { x0 += x1; x1 = TF_ROT(x1, r); x1 ^= x0; } while (0)
  x0 += k0; x1 += k1;
  TF_RND(13); TF_RND(15); TF_RND(26); TF_RND(6);
  x0 += k1; x1 += ks2 + 1u;
  TF_RND(17); TF_RND(29); TF_RND(16); TF_RND(24);
  x0 += ks2; x1 += k0 + 2u;
  TF_RND(13); TF_RND(15); TF_RND(26); TF_RND(6);
  x0 += k0; x1 += k1 + 3u;
  TF_RND(17); TF_RND(29); TF_RND(16); TF_RND(24);
  x0 += k1; x1 += ks2 + 4u;
  TF_RND(13); TF_RND(15); TF_RND(26); TF_RND(6);
  x0 += ks2; x1 += k0 + 5u;
#undef TF_RND
#undef TF_ROT
  return {x0, x1};
}

__host__ __device__ __forceinline__ uint32_t random_bits_at(uint32_t ka, uint32_t kb,
                                                            uint32_t idx) {
  TF2 r = threefry2x32(ka, kb, 0u, idx);
  return r.a ^ r.b;
}

// XLA/CHLO ErfInv f32 (bit-exact, verified r1-r4).
__device__ __forceinline__ float erfinv_f32_xla(float x) {
  float xx = __fmul_rn(x, x);
  float v  = -xx;
  float w;
  if (fabsf(v) < 1e-4f) {
    float t = __fmul_rn(__fadd_rn(__fmul_rn(-0.5f, v), 1.0f), v);
    w = -t;
  } else {
    float t = __fadd_rn(v, 1.0f);
    w = -(float)log((double)t);
  }
  float p;
  if (w < 5.0f) {
    float ww = __fadd_rn(w, -2.5f);
    p = 2.81022636e-08f;
    p = __fadd_rn( 3.43273939e-07f, __fmul_rn(p, ww));
    p = __fadd_rn(-3.5233877e-06f,  __fmul_rn(p, ww));
    p = __fadd_rn(-4.39150654e-06f, __fmul_rn(p, ww));
    p = __fadd_rn( 0.00021858087f,  __fmul_rn(p, ww));
    p = __fadd_rn(-0.00125372503f,  __fmul_rn(p, ww));
    p = __fadd_rn(-0.00417768164f,  __fmul_rn(p, ww));
    p = __fadd_rn( 0.246640727f,    __fmul_rn(p, ww));
    p = __fadd_rn( 1.50140941f,     __fmul_rn(p, ww));
  } else {
    float ww = __fadd_rn(__fsqrt_rn(w), -3.0f);
    p = -0.000200214257f;
    p = __fadd_rn( 0.000100950558f, __fmul_rn(p, ww));
    p = __fadd_rn( 0.00134934322f,  __fmul_rn(p, ww));
    p = __fadd_rn(-0.00367342844f,  __fmul_rn(p, ww));
    p = __fadd_rn( 0.00573950773f,  __fmul_rn(p, ww));
    p = __fadd_rn(-0.0076224613f,   __fmul_rn(p, ww));
    p = __fadd_rn( 0.00943887047f,  __fmul_rn(p, ww));
    p = __fadd_rn( 1.00167406f,     __fmul_rn(p, ww));
    p = __fadd_rn( 2.83297682f,     __fmul_rn(p, ww));
  }
  return __fmul_rn(p, x);
}

// Kernel 1: x_noised -> packed 64-bit total-order key; zero done[].
__global__ __launch_bounds__(64)
void noise_kernel(const float* __restrict__ scores, uint64_t* __restrict__ k64,
                  uint32_t* __restrict__ done,
                  uint32_t k1a, uint32_t k1b, uint32_t k3a, uint32_t k3b,
                  uint32_t rowmask) {
  if (blockIdx.x == 0 && threadIdx.x < 8) done[threadIdx.x] = 0;

  int e = blockIdx.x * 64 + threadIdx.x;   // 32768
  int b = e >> 12;

  uint32_t mbits = random_bits_at(k1a, k1b, (uint32_t)e);
  bool mask = ((mbits >> 9) <= 838860u) && ((rowmask >> b) & 1u);

  float s  = scores[e];
  float sf = scores[32767 - e];
  float v  = mask ? fmaxf(s, sf) : s;
  float x  = fminf(fmaxf(v, -1.0f), 1.0f);

  uint32_t nbits = random_bits_at(k3a, k3b, (uint32_t)e);
  float f   = __uint_as_float((nbits >> 9) | 0x3f800000u);
  float f01 = __fadd_rn(f, -1.0f);
  const float lo = __uint_as_float(0xBF7FFFFFu);
  float u = __fadd_rn(__fmul_rn(f01, 2.0f), lo);
  u = fmaxf(lo, u);
  float p    = erfinv_f32_xla(u);
  float nrm  = __fmul_rn(__uint_as_float(0x3FB504F3u), p);
  float nois = __fmul_rn(nrm, 0.0009765625f);
  float xnv  = __fadd_rn(x, nois);

  uint32_t ub = __float_as_uint(xnv);
  uint32_t tk = (ub & 0x80000000u) ? ~ub : (ub | 0x80000000u);
  k64[e] = ((uint64_t)tk << 32) | (uint32_t)(e & 4095);
}

// Kernel 2: partial ranks + fence-free last-block-per-row finalize.
// partial word layout: word (row,g,q,t) holds counts of i = (4q+b)*256+t,
// b = byte lane 0..3. Store address (row*64+g)*1024 + q*256 + t -> lanes
// consecutive => coalesced write-through.
__global__ __launch_bounds__(256)
void rank_finalize_kernel(const uint64_t* __restrict__ k64,
                          uint32_t* __restrict__ partial,
                          uint32_t* __restrict__ done,
                          float* __restrict__ out) {
  int row = blockIdx.x >> 6;              // /RANK_G
  int g   = blockIdx.x & (RANK_G - 1);
  const uint64_t* rk = k64 + row * 4096;
  int t = threadIdx.x;

  uint64_t ki[IPT];
  int cnt[IPT];
#pragma unroll
  for (int m = 0; m < IPT; ++m) { ki[m] = rk[m * 256 + t]; cnt[m] = 0; }

  int j0 = g * JCHUNK;
#pragma unroll 4
  for (int j = j0; j < j0 + JCHUNK; ++j) {
    uint64_t kj = rk[j];                  // wave-uniform -> scalar load
#pragma unroll
    for (int m = 0; m < IPT; ++m) cnt[m] += (int)(kj < ki[m]);
  }

  // write-through packed partials (no L2 dirty lines -> no flush needed)
  uint32_t* pw = partial + (row * RANK_G + g) * 1024;
#pragma unroll
  for (int q = 0; q < 4; ++q) {
    uint32_t w = (uint32_t)cnt[4 * q]
               | ((uint32_t)cnt[4 * q + 1] << 8)
               | ((uint32_t)cnt[4 * q + 2] << 16)
               | ((uint32_t)cnt[4 * q + 3] << 24);
    __hip_atomic_store(&pw[q * 256 + t], w, __ATOMIC_RELAXED,
                       __HIP_MEMORY_SCOPE_SYSTEM);
  }

  __syncthreads();   // s_waitcnt vmcnt(0): write-throughs globally visible
  __shared__ int slast;
  if (t == 0)
    slast = (__hip_atomic_fetch_add(&done[row], 1u, __ATOMIC_RELAXED,
                                    __HIP_MEMORY_SCOPE_AGENT)
             == (uint32_t)(RANK_G - 1));
  __syncthreads();
  if (!slast) return;

  // --- last block of this row: finalize (cache-bypass reads from MALL) ---
  const uint32_t* prow = partial + row * RANK_G * 1024;
  int acc[16];
#pragma unroll
  for (int q = 0; q < 16; ++q) acc[q] = 0;

#pragma unroll 8
  for (int gg = 0; gg < RANK_G; ++gg) {
#pragma unroll
    for (int q = 0; q < 4; ++q) {
      uint32_t w = __hip_atomic_load(&prow[gg * 1024 + q * 256 + t],
                                     __ATOMIC_RELAXED,
                                     __HIP_MEMORY_SCOPE_SYSTEM);
      acc[4 * q]     += (int)(w & 0xFFu);
      acc[4 * q + 1] += (int)((w >> 8) & 0xFFu);
      acc[4 * q + 2] += (int)((w >> 16) & 0xFFu);
      acc[4 * q + 3] += (int)((w >> 24) & 0xFFu);
    }
  }

#pragma unroll
  for (int q = 0; q < 4; ++q) {
#pragma unroll
    for (int b = 0; b < 4; ++b) {
      int r = acc[4 * q + b];
      if (r >= 2048) {
        int j = r - 2048;
        int i = (4 * q + b) * 256 + t;
        out[row * 2048 + j] = (float)i;
        out[16384 + row * 2048 + j] = fminf(__fdiv_rn((float)j, 204.8f), 1.0f);
      }
    }
  }
}

extern "C" void kernel_launch(void* const* d_in, const int* in_sizes, int n_in,
                              void* d_out, int out_size, void* d_ws, size_t ws_size,
                              hipStream_t stream) {
  const float* scores = (const float*)d_in[0];
  float* out = (float*)d_out;

  uint64_t* k64     = (uint64_t*)d_ws;                              // 256 KB
  uint32_t* partial = (uint32_t*)((uint8_t*)d_ws + 32768 * 8);      // 2 MB
  uint32_t* done    = (uint32_t*)((uint8_t*)d_ws + 32768 * 8
                                  + 8 * RANK_G * 1024 * 4);

  // split(key(42), 3), partitionable layout (verified r1)
  TF2 K1 = threefry2x32(0u, 42u, 0u, 0u);
  TF2 K2 = threefry2x32(0u, 42u, 0u, 1u);
  TF2 K3 = threefry2x32(0u, 42u, 0u, 2u);

  // batch_mask rows on host: uniform(k2,(8,1)) < 0.75
  uint32_t rowmask = 0;
  for (uint32_t b = 0; b < 8; ++b) {
    uint32_t bits = random_bits_at(K2.a, K2.b, b);
    if ((bits >> 9) < 6291456u) rowmask |= (1u << b);
  }

  noise_kernel<<<512, 64, 0, stream>>>(scores, k64, done,
                                       K1.a, K1.b, K3.a, K3.b, rowmask);
  rank_finalize_kernel<<<8 * RANK_G, 256, 0, stream>>>(k64, partial, done, out);
}

// Round 6
// 20.219 us; speedup vs baseline: 3.7751x; 1.6674x over previous
//
#include <hip/hip_runtime.h>
#include <stdint.h>
#include <math.h>

// ---------------------------------------------------------------------------
// SubsetItems, round 6: bit-exact math (absmax 0.0 r1-r5). Back to 3 plain
// dispatches (r4/r5 lesson: node overhead ~1us; cross-block fencing is the
// expensive thing, the implicit inter-dispatch flush is cheap and correct).
// Rank phase redesigned: r3's linear 64-cmp scan was VCC-serialized (~8cyc/
// cmp latency-bound). Now: per block sort its 64 j-keys (rank-sort, unique
// keys) then per-i branchless lower_bound binary search (7 LDS steps).
//   k1 noise    -> packed 64-bit total-order keys (tk<<32 | col)
//   k2 rank     -> u8x4-packed partial counts via sort + binary search
//   k3 finalize -> block=(row,q): sum 64 partials/byte-lane, scatter output
// ---------------------------------------------------------------------------

#define RANK_G 64
#define JCHUNK 64     // per-(i,g) count <= 64, fits u8
#define IPT    16

struct TF2 { uint32_t a, b; };

__host__ __device__ inline TF2 threefry2x32(uint32_t k0, uint32_t k1,
                                            uint32_t x0, uint32_t x1) {
  const uint32_t ks2 = k0 ^ k1 ^ 0x1BD11BDAu;
#define TF_ROT(v, d) (uint32_t)(((v) << (d)) | ((v) >> (32 - (d))))
#define TF_RND(r) do { x0 += x1; x1 = TF_ROT(x1, r); x1 ^= x0; } while (0)
  x0 += k0; x1 += k1;
  TF_RND(13); TF_RND(15); TF_RND(26); TF_RND(6);
  x0 += k1; x1 += ks2 + 1u;
  TF_RND(17); TF_RND(29); TF_RND(16); TF_RND(24);
  x0 += ks2; x1 += k0 + 2u;
  TF_RND(13); TF_RND(15); TF_RND(26); TF_RND(6);
  x0 += k0; x1 += k1 + 3u;
  TF_RND(17); TF_RND(29); TF_RND(16); TF_RND(24);
  x0 += k1; x1 += ks2 + 4u;
  TF_RND(13); TF_RND(15); TF_RND(26); TF_RND(6);
  x0 += ks2; x1 += k0 + 5u;
#undef TF_RND
#undef TF_ROT
  return {x0, x1};
}

__host__ __device__ __forceinline__ uint32_t random_bits_at(uint32_t ka, uint32_t kb,
                                                            uint32_t idx) {
  TF2 r = threefry2x32(ka, kb, 0u, idx);
  return r.a ^ r.b;
}

// XLA/CHLO ErfInv f32 (bit-exact, verified r1-r5).
__device__ __forceinline__ float erfinv_f32_xla(float x) {
  float xx = __fmul_rn(x, x);
  float v  = -xx;
  float w;
  if (fabsf(v) < 1e-4f) {
    float t = __fmul_rn(__fadd_rn(__fmul_rn(-0.5f, v), 1.0f), v);
    w = -t;
  } else {
    float t = __fadd_rn(v, 1.0f);
    w = -(float)log((double)t);
  }
  float p;
  if (w < 5.0f) {
    float ww = __fadd_rn(w, -2.5f);
    p = 2.81022636e-08f;
    p = __fadd_rn( 3.43273939e-07f, __fmul_rn(p, ww));
    p = __fadd_rn(-3.5233877e-06f,  __fmul_rn(p, ww));
    p = __fadd_rn(-4.39150654e-06f, __fmul_rn(p, ww));
    p = __fadd_rn( 0.00021858087f,  __fmul_rn(p, ww));
    p = __fadd_rn(-0.00125372503f,  __fmul_rn(p, ww));
    p = __fadd_rn(-0.00417768164f,  __fmul_rn(p, ww));
    p = __fadd_rn( 0.246640727f,    __fmul_rn(p, ww));
    p = __fadd_rn( 1.50140941f,     __fmul_rn(p, ww));
  } else {
    float ww = __fadd_rn(__fsqrt_rn(w), -3.0f);
    p = -0.000200214257f;
    p = __fadd_rn( 0.000100950558f, __fmul_rn(p, ww));
    p = __fadd_rn( 0.00134934322f,  __fmul_rn(p, ww));
    p = __fadd_rn(-0.00367342844f,  __fmul_rn(p, ww));
    p = __fadd_rn( 0.00573950773f,  __fmul_rn(p, ww));
    p = __fadd_rn(-0.0076224613f,   __fmul_rn(p, ww));
    p = __fadd_rn( 0.00943887047f,  __fmul_rn(p, ww));
    p = __fadd_rn( 1.00167406f,     __fmul_rn(p, ww));
    p = __fadd_rn( 2.83297682f,     __fmul_rn(p, ww));
  }
  return __fmul_rn(p, x);
}

// Kernel 1: x_noised -> packed 64-bit total-order key.
__global__ __launch_bounds__(256)
void noise_kernel(const float* __restrict__ scores, uint64_t* __restrict__ k64,
                  uint32_t k1a, uint32_t k1b, uint32_t k3a, uint32_t k3b,
                  uint32_t rowmask) {
  int e = blockIdx.x * 256 + threadIdx.x;   // 32768
  int b = e >> 12;

  uint32_t mbits = random_bits_at(k1a, k1b, (uint32_t)e);
  bool mask = ((mbits >> 9) <= 838860u) && ((rowmask >> b) & 1u);

  float s  = scores[e];
  float sf = scores[32767 - e];
  float v  = mask ? fmaxf(s, sf) : s;
  float x  = fminf(fmaxf(v, -1.0f), 1.0f);

  uint32_t nbits = random_bits_at(k3a, k3b, (uint32_t)e);
  float f   = __uint_as_float((nbits >> 9) | 0x3f800000u);
  float f01 = __fadd_rn(f, -1.0f);
  const float lo = __uint_as_float(0xBF7FFFFFu);
  float u = __fadd_rn(__fmul_rn(f01, 2.0f), lo);
  u = fmaxf(lo, u);
  float p    = erfinv_f32_xla(u);
  float nrm  = __fmul_rn(__uint_as_float(0x3FB504F3u), p);
  float nois = __fmul_rn(nrm, 0.0009765625f);
  float xnv  = __fadd_rn(x, nois);

  uint32_t ub = __float_as_uint(xnv);
  uint32_t tk = (ub & 0x80000000u) ? ~ub : (ub | 0x80000000u);
  k64[e] = ((uint64_t)tk << 32) | (uint32_t)(e & 4095);
}

// Kernel 2: partial ranks via per-block j-chunk sort + binary search.
// partial word (row,g,q,t) packs counts of i = (4q+b)*256+t in byte b.
__global__ __launch_bounds__(256)
void rank_kernel(const uint64_t* __restrict__ k64,
                 uint32_t* __restrict__ partial) {
  __shared__ uint64_t jraw[JCHUNK];
  __shared__ uint64_t jsrt[JCHUNK];
  int row = blockIdx.x >> 6;              // /RANK_G
  int g   = blockIdx.x & (RANK_G - 1);
  const uint64_t* rk = k64 + row * 4096;
  int t = threadIdx.x;

  // load i-keys first (independent global loads overlap the sort)
  uint64_t ki[IPT];
#pragma unroll
  for (int m = 0; m < IPT; ++m) ki[m] = rk[m * 256 + t];

  if (t < JCHUNK) jraw[t] = rk[g * JCHUNK + t];
  __syncthreads();
  if (t < JCHUNK) {
    uint64_t kt = jraw[t];
    int r = 0;
#pragma unroll 8
    for (int u = 0; u < JCHUNK; ++u) r += (int)(jraw[u] < kt);
    jsrt[r] = kt;                         // keys unique -> exact ranks
  }
  __syncthreads();

  // branchless lower_bound: cnt = #{j in chunk : key_j < ki}
  int cnt[IPT];
#pragma unroll
  for (int m = 0; m < IPT; ++m) {
    uint64_t k = ki[m];
    int pos = 0;
    pos += (jsrt[pos + 31] < k) ? 32 : 0;
    pos += (jsrt[pos + 15] < k) ? 16 : 0;
    pos += (jsrt[pos + 7]  < k) ? 8  : 0;
    pos += (jsrt[pos + 3]  < k) ? 4  : 0;
    pos += (jsrt[pos + 1]  < k) ? 2  : 0;
    pos += (jsrt[pos]      < k) ? 1  : 0;
    pos += (jsrt[pos]      < k) ? 1  : 0;   // final correction (pos<=63 here)
    cnt[m] = pos;
  }

  uint32_t* pw = partial + (row * RANK_G + g) * 1024;
#pragma unroll
  for (int q = 0; q < 4; ++q) {
    uint32_t w = (uint32_t)cnt[4 * q]
               | ((uint32_t)cnt[4 * q + 1] << 8)
               | ((uint32_t)cnt[4 * q + 2] << 16)
               | ((uint32_t)cnt[4 * q + 3] << 24);
    pw[q * 256 + t] = w;
  }
}

// Kernel 3: block=(row,q). Sum 64 partial words, extract 4 byte-lanes,
// scatter idx + weight. Exactly 2 MB read, coalesced.
__global__ __launch_bounds__(256)
void finalize_kernel(const uint32_t* __restrict__ partial,
                     float* __restrict__ out) {
  int row = blockIdx.x >> 2;
  int q   = blockIdx.x & 3;
  int t   = threadIdx.x;
  const uint32_t* prow = partial + row * RANK_G * 1024 + q * 256 + t;

  int acc0 = 0, acc1 = 0, acc2 = 0, acc3 = 0;
#pragma unroll 8
  for (int g = 0; g < RANK_G; ++g) {
    uint32_t w = prow[g * 1024];
    acc0 += (int)(w & 0xFFu);
    acc1 += (int)((w >> 8) & 0xFFu);
    acc2 += (int)((w >> 16) & 0xFFu);
    acc3 += (int)((w >> 24) & 0xFFu);
  }

  int accs[4] = {acc0, acc1, acc2, acc3};
#pragma unroll
  for (int b = 0; b < 4; ++b) {
    int r = accs[b];
    if (r >= 2048) {
      int j = r - 2048;
      int i = (4 * q + b) * 256 + t;
      out[row * 2048 + j] = (float)i;
      out[16384 + row * 2048 + j] = fminf(__fdiv_rn((float)j, 204.8f), 1.0f);
    }
  }
}

extern "C" void kernel_launch(void* const* d_in, const int* in_sizes, int n_in,
                              void* d_out, int out_size, void* d_ws, size_t ws_size,
                              hipStream_t stream) {
  const float* scores = (const float*)d_in[0];
  float* out = (float*)d_out;

  uint64_t* k64     = (uint64_t*)d_ws;                          // 256 KB
  uint32_t* partial = (uint32_t*)((uint8_t*)d_ws + 32768 * 8);  // 2 MB

  // split(key(42), 3), partitionable layout (verified r1)
  TF2 K1 = threefry2x32(0u, 42u, 0u, 0u);
  TF2 K2 = threefry2x32(0u, 42u, 0u, 1u);
  TF2 K3 = threefry2x32(0u, 42u, 0u, 2u);

  // batch_mask rows on host: uniform(k2,(8,1)) < 0.75
  uint32_t rowmask = 0;
  for (uint32_t b = 0; b < 8; ++b) {
    uint32_t bits = random_bits_at(K2.a, K2.b, b);
    if ((bits >> 9) < 6291456u) rowmask |= (1u << b);
  }

  noise_kernel<<<128, 256, 0, stream>>>(scores, k64,
                                        K1.a, K1.b, K3.a, K3.b, rowmask);
  rank_kernel<<<8 * RANK_G, 256, 0, stream>>>(k64, partial);
  finalize_kernel<<<32, 256, 0, stream>>>(partial, out);
}

// Round 7
// 19.471 us; speedup vs baseline: 3.9203x; 1.0384x over previous
//
#include <hip/hip_runtime.h>
#include <stdint.h>
#include <math.h>

// ---------------------------------------------------------------------------
// SubsetItems, round 7: bit-exact math (absmax 0.0 r1-r6). 3 dispatches.
// Change vs r6: rank's binary search restructured SEARCH-MAJOR -> STEP-MAJOR:
// each of 7 lower_bound steps issues 16 independent ds_reads (one per search)
// then one wait, instead of 16 serial 7-deep dependent chains. Finalize
// unroll 8 -> 16 outstanding loads.
//   k1 noise    -> packed 64-bit total-order keys (tk<<32 | col)
//   k2 rank     -> per-block j-chunk sort + step-major lower_bound, u8x4 pack
//   k3 finalize -> block=(row,q): sum 64 partials/byte-lane, scatter output
// ---------------------------------------------------------------------------

#define RANK_G 64
#define JCHUNK 64     // per-(i,g) count <= 64, fits u8
#define IPT    16

struct TF2 { uint32_t a, b; };

__host__ __device__ inline TF2 threefry2x32(uint32_t k0, uint32_t k1,
                                            uint32_t x0, uint32_t x1) {
  const uint32_t ks2 = k0 ^ k1 ^ 0x1BD11BDAu;
#define TF_ROT(v, d) (uint32_t)(((v) << (d)) | ((v) >> (32 - (d))))
#define TF_RND(r) do { x0 += x1; x1 = TF_ROT(x1, r); x1 ^= x0; } while (0)
  x0 += k0; x1 += k1;
  TF_RND(13); TF_RND(15); TF_RND(26); TF_RND(6);
  x0 += k1; x1 += ks2 + 1u;
  TF_RND(17); TF_RND(29); TF_RND(16); TF_RND(24);
  x0 += ks2; x1 += k0 + 2u;
  TF_RND(13); TF_RND(15); TF_RND(26); TF_RND(6);
  x0 += k0; x1 += k1 + 3u;
  TF_RND(17); TF_RND(29); TF_RND(16); TF_RND(24);
  x0 += k1; x1 += ks2 + 4u;
  TF_RND(13); TF_RND(15); TF_RND(26); TF_RND(6);
  x0 += ks2; x1 += k0 + 5u;
#undef TF_RND
#undef TF_ROT
  return {x0, x1};
}

__host__ __device__ __forceinline__ uint32_t random_bits_at(uint32_t ka, uint32_t kb,
                                                            uint32_t idx) {
  TF2 r = threefry2x32(ka, kb, 0u, idx);
  return r.a ^ r.b;
}

// XLA/CHLO ErfInv f32 (bit-exact, verified r1-r6).
__device__ __forceinline__ float erfinv_f32_xla(float x) {
  float xx = __fmul_rn(x, x);
  float v  = -xx;
  float w;
  if (fabsf(v) < 1e-4f) {
    float t = __fmul_rn(__fadd_rn(__fmul_rn(-0.5f, v), 1.0f), v);
    w = -t;
  } else {
    float t = __fadd_rn(v, 1.0f);
    w = -(float)log((double)t);
  }
  float p;
  if (w < 5.0f) {
    float ww = __fadd_rn(w, -2.5f);
    p = 2.81022636e-08f;
    p = __fadd_rn( 3.43273939e-07f, __fmul_rn(p, ww));
    p = __fadd_rn(-3.5233877e-06f,  __fmul_rn(p, ww));
    p = __fadd_rn(-4.39150654e-06f, __fmul_rn(p, ww));
    p = __fadd_rn( 0.00021858087f,  __fmul_rn(p, ww));
    p = __fadd_rn(-0.00125372503f,  __fmul_rn(p, ww));
    p = __fadd_rn(-0.00417768164f,  __fmul_rn(p, ww));
    p = __fadd_rn( 0.246640727f,    __fmul_rn(p, ww));
    p = __fadd_rn( 1.50140941f,     __fmul_rn(p, ww));
  } else {
    float ww = __fadd_rn(__fsqrt_rn(w), -3.0f);
    p = -0.000200214257f;
    p = __fadd_rn( 0.000100950558f, __fmul_rn(p, ww));
    p = __fadd_rn( 0.00134934322f,  __fmul_rn(p, ww));
    p = __fadd_rn(-0.00367342844f,  __fmul_rn(p, ww));
    p = __fadd_rn( 0.00573950773f,  __fmul_rn(p, ww));
    p = __fadd_rn(-0.0076224613f,   __fmul_rn(p, ww));
    p = __fadd_rn( 0.00943887047f,  __fmul_rn(p, ww));
    p = __fadd_rn( 1.00167406f,     __fmul_rn(p, ww));
    p = __fadd_rn( 2.83297682f,     __fmul_rn(p, ww));
  }
  return __fmul_rn(p, x);
}

// Kernel 1: x_noised -> packed 64-bit total-order key.
__global__ __launch_bounds__(256)
void noise_kernel(const float* __restrict__ scores, uint64_t* __restrict__ k64,
                  uint32_t k1a, uint32_t k1b, uint32_t k3a, uint32_t k3b,
                  uint32_t rowmask) {
  int e = blockIdx.x * 256 + threadIdx.x;   // 32768
  int b = e >> 12;

  uint32_t mbits = random_bits_at(k1a, k1b, (uint32_t)e);
  bool mask = ((mbits >> 9) <= 838860u) && ((rowmask >> b) & 1u);

  float s  = scores[e];
  float sf = scores[32767 - e];
  float v  = mask ? fmaxf(s, sf) : s;
  float x  = fminf(fmaxf(v, -1.0f), 1.0f);

  uint32_t nbits = random_bits_at(k3a, k3b, (uint32_t)e);
  float f   = __uint_as_float((nbits >> 9) | 0x3f800000u);
  float f01 = __fadd_rn(f, -1.0f);
  const float lo = __uint_as_float(0xBF7FFFFFu);
  float u = __fadd_rn(__fmul_rn(f01, 2.0f), lo);
  u = fmaxf(lo, u);
  float p    = erfinv_f32_xla(u);
  float nrm  = __fmul_rn(__uint_as_float(0x3FB504F3u), p);
  float nois = __fmul_rn(nrm, 0.0009765625f);
  float xnv  = __fadd_rn(x, nois);

  uint32_t ub = __float_as_uint(xnv);
  uint32_t tk = (ub & 0x80000000u) ? ~ub : (ub | 0x80000000u);
  k64[e] = ((uint64_t)tk << 32) | (uint32_t)(e & 4095);
}

// Kernel 2: partial ranks via per-block j-chunk sort + STEP-MAJOR lower_bound.
// partial word (row,g,q,t) packs counts of i = (4q+b)*256+t in byte b.
__global__ __launch_bounds__(256)
void rank_kernel(const uint64_t* __restrict__ k64,
                 uint32_t* __restrict__ partial) {
  __shared__ uint64_t jraw[JCHUNK];
  __shared__ uint64_t jsrt[JCHUNK];
  int row = blockIdx.x >> 6;              // /RANK_G
  int g   = blockIdx.x & (RANK_G - 1);
  const uint64_t* rk = k64 + row * 4096;
  int t = threadIdx.x;

  // load i-keys first (independent global loads overlap the sort)
  uint64_t ki[IPT];
#pragma unroll
  for (int m = 0; m < IPT; ++m) ki[m] = rk[m * 256 + t];

  if (t < JCHUNK) jraw[t] = rk[g * JCHUNK + t];
  __syncthreads();
  if (t < JCHUNK) {
    uint64_t kt = jraw[t];
    int r = 0;
#pragma unroll 8
    for (int u = 0; u < JCHUNK; ++u) r += (int)(jraw[u] < kt);
    jsrt[r] = kt;                         // keys unique -> exact ranks
  }
  __syncthreads();

  // step-major branchless lower_bound: cnt = #{j in chunk : key_j < ki}.
  // Per step: 16 independent ds_reads issued together, one wait, 16 updates.
  int pos[IPT];
#pragma unroll
  for (int m = 0; m < IPT; ++m) pos[m] = 0;

  const int offs[7] = {31, 15, 7, 3, 1, 0, 0};
  const int incs[7] = {32, 16, 8, 4, 2, 1, 1};
#pragma unroll
  for (int s = 0; s < 7; ++s) {
    uint64_t v[IPT];
#pragma unroll
    for (int m = 0; m < IPT; ++m) v[m] = jsrt[pos[m] + offs[s]];
#pragma unroll
    for (int m = 0; m < IPT; ++m) pos[m] += (v[m] < ki[m]) ? incs[s] : 0;
  }

  uint32_t* pw = partial + (row * RANK_G + g) * 1024;
#pragma unroll
  for (int q = 0; q < 4; ++q) {
    uint32_t w = (uint32_t)pos[4 * q]
               | ((uint32_t)pos[4 * q + 1] << 8)
               | ((uint32_t)pos[4 * q + 2] << 16)
               | ((uint32_t)pos[4 * q + 3] << 24);
    pw[q * 256 + t] = w;
  }
}

// Kernel 3: block=(row,q). Sum 64 partial words, extract 4 byte-lanes,
// scatter idx + weight. Exactly 2 MB read, coalesced, 16 loads in flight.
__global__ __launch_bounds__(256)
void finalize_kernel(const uint32_t* __restrict__ partial,
                     float* __restrict__ out) {
  int row = blockIdx.x >> 2;
  int q   = blockIdx.x & 3;
  int t   = threadIdx.x;
  const uint32_t* prow = partial + row * RANK_G * 1024 + q * 256 + t;

  int acc0 = 0, acc1 = 0, acc2 = 0, acc3 = 0;
#pragma unroll 16
  for (int g = 0; g < RANK_G; ++g) {
    uint32_t w = prow[g * 1024];
    acc0 += (int)(w & 0xFFu);
    acc1 += (int)((w >> 8) & 0xFFu);
    acc2 += (int)((w >> 16) & 0xFFu);
    acc3 += (int)((w >> 24) & 0xFFu);
  }

  int accs[4] = {acc0, acc1, acc2, acc3};
#pragma unroll
  for (int b = 0; b < 4; ++b) {
    int r = accs[b];
    if (r >= 2048) {
      int j = r - 2048;
      int i = (4 * q + b) * 256 + t;
      out[row * 2048 + j] = (float)i;
      out[16384 + row * 2048 + j] = fminf(__fdiv_rn((float)j, 204.8f), 1.0f);
    }
  }
}

extern "C" void kernel_launch(void* const* d_in, const int* in_sizes, int n_in,
                              void* d_out, int out_size, void* d_ws, size_t ws_size,
                              hipStream_t stream) {
  const float* scores = (const float*)d_in[0];
  float* out = (float*)d_out;

  uint64_t* k64     = (uint64_t*)d_ws;                          // 256 KB
  uint32_t* partial = (uint32_t*)((uint8_t*)d_ws + 32768 * 8);  // 2 MB

  // split(key(42), 3), partitionable layout (verified r1)
  TF2 K1 = threefry2x32(0u, 42u, 0u, 0u);
  TF2 K2 = threefry2x32(0u, 42u, 0u, 1u);
  TF2 K3 = threefry2x32(0u, 42u, 0u, 2u);

  // batch_mask rows on host: uniform(k2,(8,1)) < 0.75
  uint32_t rowmask = 0;
  for (uint32_t b = 0; b < 8; ++b) {
    uint32_t bits = random_bits_at(K2.a, K2.b, b);
    if ((bits >> 9) < 6291456u) rowmask |= (1u << b);
  }

  noise_kernel<<<128, 256, 0, stream>>>(scores, k64,
                                        K1.a, K1.b, K3.a, K3.b, rowmask);
  rank_kernel<<<8 * RANK_G, 256, 0, stream>>>(k64, partial);
  finalize_kernel<<<32, 256, 0, stream>>>(partial, out);
}